// Round 1
// baseline (399.072 us; speedup 1.0000x reference)
//
#include <hip/hip_runtime.h>
#include <hip/hip_bf16.h>

typedef __attribute__((ext_vector_type(8))) short short8;
typedef __attribute__((ext_vector_type(4))) float floatx4;
typedef __attribute__((ext_vector_type(4))) float float4v;
typedef __attribute__((ext_vector_type(4))) unsigned short ushort4v;

#define S_LEN 2048
#define D_MODEL 1024
#define HD 64
#define HQ 16
#define HKV 4

__device__ __forceinline__ unsigned short f2bf(float f) {
    unsigned int u = __builtin_bit_cast(unsigned int, f);
    u += 0x7fffu + ((u >> 16) & 1u);   // RNE
    return (unsigned short)(u >> 16);
}

// ---------------- f32 -> bf16 convert ----------------
__global__ void cvt_f32_bf16(const float* __restrict__ in, unsigned short* __restrict__ out, int n) {
    int i = (blockIdx.x * blockDim.x + threadIdx.x) * 4;
    int stride = gridDim.x * blockDim.x * 4;
    for (; i < n; i += stride) {
        float4v v = *(const float4v*)(in + i);
        ushort4v o;
        o.x = f2bf(v.x); o.y = f2bf(v.y); o.z = f2bf(v.z); o.w = f2bf(v.w);
        *(ushort4v*)(out + i) = o;
    }
}

// ---------------- GEMM: C[M,N] = A[M,K] * W[N,K]^T (bf16 MFMA, f32 accum) -------
// EPI 0: C f32 row-major [M,N]
// EPI 1: RoPE fused, bf16 out row-major [M,N]   (rows are b*S+s, cols h*64+d)
// EPI 2: transposed bf16 out: Vt[((b*HKV+kvh)*HD+d)*S + s]
template<int EPI>
__global__ __launch_bounds__(256) void gemm_bt(
    const unsigned short* __restrict__ A, const unsigned short* __restrict__ W,
    float* __restrict__ C, unsigned short* __restrict__ Cb,
    const float* __restrict__ fcos, const float* __restrict__ fsin,
    int M, int N, int K)
{
    const int tid  = threadIdx.x;
    const int lane = tid & 63;
    const int w    = tid >> 6;
    const int wr   = w >> 1, wc = w & 1;
    const int l15  = lane & 15, lhi = lane >> 4;
    const int row0 = blockIdx.x * 64 + wr * 32;
    const int col0 = blockIdx.y * 64 + wc * 32;

    floatx4 acc[2][2] = {};
    const unsigned short* Ap = A + (size_t)(row0 + l15) * K + lhi * 8;
    const unsigned short* Wp = W + (size_t)(col0 + l15) * K + lhi * 8;
    const size_t arow16 = (size_t)16 * K;

    for (int k0 = 0; k0 < K; k0 += 32) {
        short8 a0 = *(const short8*)(Ap + k0);
        short8 a1 = *(const short8*)(Ap + arow16 + k0);
        short8 b0 = *(const short8*)(Wp + k0);
        short8 b1 = *(const short8*)(Wp + arow16 + k0);
        acc[0][0] = __builtin_amdgcn_mfma_f32_16x16x32_bf16(a0, b0, acc[0][0], 0, 0, 0);
        acc[0][1] = __builtin_amdgcn_mfma_f32_16x16x32_bf16(a0, b1, acc[0][1], 0, 0, 0);
        acc[1][0] = __builtin_amdgcn_mfma_f32_16x16x32_bf16(a1, b0, acc[1][0], 0, 0, 0);
        acc[1][1] = __builtin_amdgcn_mfma_f32_16x16x32_bf16(a1, b1, acc[1][1], 0, 0, 0);
    }

    #pragma unroll
    for (int mi = 0; mi < 2; mi++)
    #pragma unroll
    for (int ni = 0; ni < 2; ni++)
    #pragma unroll
    for (int j = 0; j < 4; j++) {
        int row = row0 + mi * 16 + lhi * 4 + j;
        int col = col0 + ni * 16 + l15;
        float v = acc[mi][ni][j];
        if (EPI == 0) {
            C[(size_t)row * N + col] = v;
        } else if (EPI == 1) {
            float pv = __shfl_xor(v, 1);
            int sp = row & (S_LEN - 1);
            int fi = (col & (HD - 1)) >> 1;
            float c  = fcos[sp * (HD / 2) + fi];
            float sn = fsin[sp * (HD / 2) + fi];
            float o = (col & 1) ? (pv * sn + v * c) : (v * c - pv * sn);
            Cb[(size_t)row * N + col] = f2bf(o);
        } else {
            int b = row >> 11, s = row & (S_LEN - 1);
            int kvh = col >> 6, d = col & (HD - 1);
            Cb[(size_t)((b * HKV + kvh) * HD + d) * S_LEN + s] = f2bf(v);
        }
    }
}

// ---------------- Flash attention (causal, GQA) ----------------
// Q: (B,S,HQ,HD) bf16 (RoPE'd), K: (B,S,HKV,HD) bf16 (RoPE'd), Vt: (B,HKV,HD,S) bf16
// O: (B,S,HQ,HD) bf16.  One wave per 16 q-rows.
__global__ __launch_bounds__(64) void flash_attn(
    const unsigned short* __restrict__ Q, const unsigned short* __restrict__ Kk,
    const unsigned short* __restrict__ Vt, unsigned short* __restrict__ O)
{
    const int lane = threadIdx.x;
    const int l15 = lane & 15, lhi = lane >> 4;
    const int bid = blockIdx.x;
    const int qt = bid & 127;            // S/16 = 128 q-tiles
    const int h  = (bid >> 7) & 15;
    const int b  = bid >> 11;
    const int kvh = h >> 2;              // NREP = 4
    const int qbase = qt * 16;

    __shared__ unsigned short plds[16 * 72];   // stride 72 (144B, 16B-aligned, conflict-lite)

    short8 qf[2];
    {
        const unsigned short* qp = Q + ((size_t)((b * S_LEN + qbase + l15) * HQ + h)) * HD + lhi * 8;
        qf[0] = *(const short8*)(qp);
        qf[1] = *(const short8*)(qp + 32);
    }

    floatx4 oacc[4] = {};
    float m_run[4], l_run[4];
    #pragma unroll
    for (int j = 0; j < 4; j++) { m_run[j] = -__builtin_inff(); l_run[j] = 0.f; }

    const int smax = qbase + 15;
    for (int s0 = 0; s0 <= smax; s0 += 32) {
        floatx4 sacc[2] = {};
        #pragma unroll
        for (int ct = 0; ct < 2; ct++) {
            const unsigned short* kp =
                Kk + ((size_t)((b * S_LEN + s0 + ct * 16 + l15) * HKV + kvh)) * HD + lhi * 8;
            short8 k0 = *(const short8*)kp;
            short8 k1 = *(const short8*)(kp + 32);
            sacc[ct] = __builtin_amdgcn_mfma_f32_16x16x32_bf16(qf[0], k0, sacc[ct], 0, 0, 0);
            sacc[ct] = __builtin_amdgcn_mfma_f32_16x16x32_bf16(qf[1], k1, sacc[ct], 0, 0, 0);
        }

        float sv[2][4];
        #pragma unroll
        for (int ct = 0; ct < 2; ct++)
        #pragma unroll
        for (int j = 0; j < 4; j++) {
            int s_idx = s0 + ct * 16 + l15;
            int q_idx = qbase + lhi * 4 + j;
            float v = sacc[ct][j] * 0.125f;
            sv[ct][j] = (s_idx > q_idx) ? -__builtin_inff() : v;
        }

        float rmax[4], rsum[4], rr[4];
        #pragma unroll
        for (int j = 0; j < 4; j++) rmax[j] = fmaxf(sv[0][j], sv[1][j]);
        #pragma unroll
        for (int m = 1; m <= 8; m <<= 1)
            #pragma unroll
            for (int j = 0; j < 4; j++) rmax[j] = fmaxf(rmax[j], __shfl_xor(rmax[j], m));
        #pragma unroll
        for (int j = 0; j < 4; j++) {
            float mnew = fmaxf(m_run[j], rmax[j]);
            rr[j] = __expf(m_run[j] - mnew);
            m_run[j] = mnew;
        }
        float p[2][4];
        #pragma unroll
        for (int ct = 0; ct < 2; ct++)
        #pragma unroll
        for (int j = 0; j < 4; j++) p[ct][j] = __expf(sv[ct][j] - m_run[j]);
        #pragma unroll
        for (int j = 0; j < 4; j++) rsum[j] = p[0][j] + p[1][j];
        #pragma unroll
        for (int m = 1; m <= 8; m <<= 1)
            #pragma unroll
            for (int j = 0; j < 4; j++) rsum[j] += __shfl_xor(rsum[j], m);
        #pragma unroll
        for (int j = 0; j < 4; j++) l_run[j] = l_run[j] * rr[j] + rsum[j];
        #pragma unroll
        for (int ct = 0; ct < 4; ct++)
            #pragma unroll
            for (int j = 0; j < 4; j++) oacc[ct][j] *= rr[j];

        // P -> LDS (bf16), reshape to A-fragment layout
        #pragma unroll
        for (int ct = 0; ct < 2; ct++)
        #pragma unroll
        for (int j = 0; j < 4; j++)
            plds[(lhi * 4 + j) * 72 + ct * 16 + l15] = f2bf(p[ct][j]);
        __syncthreads();
        short8 pf = *(const short8*)&plds[l15 * 72 + lhi * 8];

        #pragma unroll
        for (int ct = 0; ct < 4; ct++) {
            const unsigned short* vp =
                Vt + ((size_t)((b * HKV + kvh) * HD + ct * 16 + l15)) * S_LEN + s0 + lhi * 8;
            short8 vf = *(const short8*)vp;
            oacc[ct] = __builtin_amdgcn_mfma_f32_16x16x32_bf16(pf, vf, oacc[ct], 0, 0, 0);
        }
        __syncthreads();
    }

    #pragma unroll
    for (int ct = 0; ct < 4; ct++)
    #pragma unroll
    for (int j = 0; j < 4; j++) {
        float v = oacc[ct][j] / l_run[j];
        int q = qbase + lhi * 4 + j;
        O[((size_t)((b * S_LEN + q) * HQ + h)) * HD + ct * 16 + l15] = f2bf(v);
    }
}

extern "C" void kernel_launch(void* const* d_in, const int* in_sizes, int n_in,
                              void* d_out, int out_size, void* d_ws, size_t ws_size,
                              hipStream_t stream) {
    const float* x    = (const float*)d_in[0];
    const float* wq   = (const float*)d_in[1];
    const float* wk   = (const float*)d_in[2];
    const float* wv   = (const float*)d_in[3];
    const float* wo   = (const float*)d_in[4];
    const float* fcos = (const float*)d_in[5];
    const float* fsin = (const float*)d_in[6];
    float* out = (float*)d_out;

    const int M = 2 * S_LEN;              // 4096
    char* ws = (char*)d_ws;
    unsigned short* xb  = (unsigned short*)(ws);
    unsigned short* wqb = (unsigned short*)(ws + 8388608);
    unsigned short* wkb = (unsigned short*)(ws + 10485760);
    unsigned short* wvb = (unsigned short*)(ws + 11010048);
    unsigned short* wob = (unsigned short*)(ws + 11534336);
    unsigned short* Qb  = (unsigned short*)(ws + 13631488);
    unsigned short* Kb  = (unsigned short*)(ws + 22020096);
    unsigned short* Vtb = (unsigned short*)(ws + 24117248);
    unsigned short* Ab  = (unsigned short*)(ws + 26214400);

    cvt_f32_bf16<<<1024, 256, 0, stream>>>(x,  xb,  M * D_MODEL);
    cvt_f32_bf16<<<256,  256, 0, stream>>>(wq, wqb, D_MODEL * D_MODEL);
    cvt_f32_bf16<<<64,   256, 0, stream>>>(wk, wkb, HKV * HD * D_MODEL);
    cvt_f32_bf16<<<64,   256, 0, stream>>>(wv, wvb, HKV * HD * D_MODEL);
    cvt_f32_bf16<<<256,  256, 0, stream>>>(wo, wob, D_MODEL * D_MODEL);

    gemm_bt<1><<<dim3(M / 64, 16), 256, 0, stream>>>(xb, wqb, nullptr, Qb,  fcos, fsin, M, 1024, 1024);
    gemm_bt<1><<<dim3(M / 64, 4),  256, 0, stream>>>(xb, wkb, nullptr, Kb,  fcos, fsin, M, 256,  1024);
    gemm_bt<2><<<dim3(M / 64, 4),  256, 0, stream>>>(xb, wvb, nullptr, Vtb, nullptr, nullptr, M, 256, 1024);

    flash_attn<<<2 * 16 * (S_LEN / 16), 64, 0, stream>>>(Qb, Kb, Vtb, Ab);

    gemm_bt<0><<<dim3(M / 64, 16), 256, 0, stream>>>(Ab, wob, out, nullptr, nullptr, nullptr, M, 1024, 1024);
}

// Round 2
// 248.337 us; speedup vs baseline: 1.6070x; 1.6070x over previous
//
#include <hip/hip_runtime.h>
#include <hip/hip_bf16.h>

typedef __attribute__((ext_vector_type(8))) short short8;
typedef __attribute__((ext_vector_type(4))) float floatx4;
typedef __attribute__((ext_vector_type(4))) float float4v;
typedef __attribute__((ext_vector_type(4))) unsigned short ushort4v;

#define S_LEN 2048
#define D_MODEL 1024
#define HD 64
#define HQ 16
#define HKV 4

__device__ __forceinline__ unsigned short f2bf(float f) {
    unsigned int u = __builtin_bit_cast(unsigned int, f);
    u += 0x7fffu + ((u >> 16) & 1u);   // RNE
    return (unsigned short)(u >> 16);
}

__device__ __forceinline__ unsigned int cvt_pk_bf16(float lo, float hi) {
    unsigned int r;
    asm volatile("v_cvt_pk_bf16_f32 %0, %1, %2" : "=v"(r) : "v"(lo), "v"(hi));
    return r;
}

// ---------------- f32 -> bf16 convert ----------------
__global__ void cvt_f32_bf16(const float* __restrict__ in, unsigned short* __restrict__ out, int n) {
    int i = (blockIdx.x * blockDim.x + threadIdx.x) * 4;
    int stride = gridDim.x * blockDim.x * 4;
    for (; i < n; i += stride) {
        float4v v = *(const float4v*)(in + i);
        ushort4v o;
        o.x = f2bf(v.x); o.y = f2bf(v.y); o.z = f2bf(v.z); o.w = f2bf(v.w);
        *(ushort4v*)(out + i) = o;
    }
}

// ---------------- GEMM: C[M,N] = A[M,K] * W[N,K]^T (bf16 MFMA, f32 accum) -------
// EPI 0: C f32 row-major [M,N]
// EPI 1: RoPE fused, bf16 out row-major [M,N]
// EPI 2: transposed bf16 out: Vt[((b*HKV+kvh)*HD+d)*S + s]
template<int EPI>
__global__ __launch_bounds__(256) void gemm_bt(
    const unsigned short* __restrict__ A, const unsigned short* __restrict__ W,
    float* __restrict__ C, unsigned short* __restrict__ Cb,
    const float* __restrict__ fcos, const float* __restrict__ fsin,
    int M, int N, int K)
{
    const int tid  = threadIdx.x;
    const int lane = tid & 63;
    const int w    = tid >> 6;
    const int wr   = w >> 1, wc = w & 1;
    const int l15  = lane & 15, lhi = lane >> 4;
    const int row0 = blockIdx.x * 64 + wr * 32;
    const int col0 = blockIdx.y * 64 + wc * 32;

    floatx4 acc[2][2] = {};
    const unsigned short* Ap = A + (size_t)(row0 + l15) * K + lhi * 8;
    const unsigned short* Wp = W + (size_t)(col0 + l15) * K + lhi * 8;
    const size_t arow16 = (size_t)16 * K;

    for (int k0 = 0; k0 < K; k0 += 32) {
        short8 a0 = *(const short8*)(Ap + k0);
        short8 a1 = *(const short8*)(Ap + arow16 + k0);
        short8 b0 = *(const short8*)(Wp + k0);
        short8 b1 = *(const short8*)(Wp + arow16 + k0);
        acc[0][0] = __builtin_amdgcn_mfma_f32_16x16x32_bf16(a0, b0, acc[0][0], 0, 0, 0);
        acc[0][1] = __builtin_amdgcn_mfma_f32_16x16x32_bf16(a0, b1, acc[0][1], 0, 0, 0);
        acc[1][0] = __builtin_amdgcn_mfma_f32_16x16x32_bf16(a1, b0, acc[1][0], 0, 0, 0);
        acc[1][1] = __builtin_amdgcn_mfma_f32_16x16x32_bf16(a1, b1, acc[1][1], 0, 0, 0);
    }

    #pragma unroll
    for (int mi = 0; mi < 2; mi++)
    #pragma unroll
    for (int ni = 0; ni < 2; ni++)
    #pragma unroll
    for (int j = 0; j < 4; j++) {
        int row = row0 + mi * 16 + lhi * 4 + j;
        int col = col0 + ni * 16 + l15;
        float v = acc[mi][ni][j];
        if (EPI == 0) {
            C[(size_t)row * N + col] = v;
        } else if (EPI == 1) {
            float pv = __shfl_xor(v, 1);
            int sp = row & (S_LEN - 1);
            int fi = (col & (HD - 1)) >> 1;
            float c  = fcos[sp * (HD / 2) + fi];
            float sn = fsin[sp * (HD / 2) + fi];
            float o = (col & 1) ? (pv * sn + v * c) : (v * c - pv * sn);
            Cb[(size_t)row * N + col] = f2bf(o);
        } else {
            int b = row >> 11, s = row & (S_LEN - 1);
            int kvh = col >> 6, d = col & (HD - 1);
            Cb[(size_t)((b * HKV + kvh) * HD + d) * S_LEN + s] = f2bf(v);
        }
    }
}

// ---------------- Flash attention v2 (swapped QK^T, causal, GQA) ----------------
// Q: (B,S,HQ,HD) bf16 RoPE'd, K: (B,S,HKV,HD) bf16 RoPE'd, Vt: (B,HKV,HD,S) bf16
// O: (B,S,HQ,HD) bf16.  One wave per 32 q-rows (2 q-subtiles of 16), KVBLK=64.
// Swapped: S[s][q] = mfma(Kfrag, Qfrag) -> s is lane-local (lhi*4+j, st), q = l15.
__global__ __launch_bounds__(64) void flash_attn(
    const unsigned short* __restrict__ Q, const unsigned short* __restrict__ Kk,
    const unsigned short* __restrict__ Vt, unsigned short* __restrict__ O)
{
    const int lane = threadIdx.x;
    const int l15 = lane & 15, lhi = lane >> 4;
    const int bid = blockIdx.x;
    // bid = qc_raw*32 + b*16 + h ; heavy q-chunks first
    const int h  = bid & 15;
    const int b  = (bid >> 4) & 1;
    const int qc = 63 - (bid >> 5);
    const int kvh = h >> 2;
    const int qbase = qc * 32;

    __shared__ __align__(16) unsigned short plds[2][16][72];

    // Q fragments (B-frag: lane l15 = q col, k = d = ks*32 + lhi*8)
    short8 qf[2][2];
    #pragma unroll
    for (int qi = 0; qi < 2; qi++) {
        const unsigned short* qp =
            Q + ((size_t)(b * S_LEN + qbase + qi * 16 + l15) * HQ + h) * HD + lhi * 8;
        qf[qi][0] = *(const short8*)qp;
        qf[qi][1] = *(const short8*)(qp + 32);
    }

    floatx4 oacc[2][4] = {};
    float m_run[2] = {-1e30f, -1e30f};
    float l_run[2] = {0.f, 0.f};

    const unsigned short* kbase = Kk + ((size_t)(b * S_LEN) * HKV + kvh) * HD + lhi * 8;
    const unsigned short* vbase = Vt + (size_t)((b * HKV + kvh) * HD + l15) * S_LEN + lhi * 8;

    for (int s0 = 0; s0 <= qbase + 31; s0 += 64) {
        // K fragments (A-frag: lane l15 = s row, k = d)
        short8 kf[4][2];
        #pragma unroll
        for (int st = 0; st < 4; st++) {
            const unsigned short* kp = kbase + (size_t)(s0 + st * 16 + l15) * (HKV * HD);
            kf[st][0] = *(const short8*)kp;
            kf[st][1] = *(const short8*)(kp + 32);
        }
        // V fragments (A-frag for PV: lane l15 = d row, k = s)
        short8 vf[4][2];
        #pragma unroll
        for (int dct = 0; dct < 4; dct++) {
            const unsigned short* vp = vbase + (size_t)(dct * 16) * S_LEN + s0;
            vf[dct][0] = *(const short8*)vp;
            vf[dct][1] = *(const short8*)(vp + 32);
        }

        #pragma unroll
        for (int qi = 0; qi < 2; qi++) {
            const int qb = qbase + qi * 16;
            if (s0 > qb) continue;           // subtile entirely above diagonal

            floatx4 sacc[4] = {};
            #pragma unroll
            for (int st = 0; st < 4; st++) {
                sacc[st] = __builtin_amdgcn_mfma_f32_16x16x32_bf16(kf[st][0], qf[qi][0], sacc[st], 0, 0, 0);
                sacc[st] = __builtin_amdgcn_mfma_f32_16x16x32_bf16(kf[st][1], qf[qi][1], sacc[st], 0, 0, 0);
            }

            const int q = qb + l15;
            if (s0 + 63 > qb) {              // diagonal tile: apply causal mask
                #pragma unroll
                for (int st = 0; st < 4; st++)
                #pragma unroll
                for (int j = 0; j < 4; j++) {
                    int s = s0 + st * 16 + lhi * 4 + j;
                    if (s > q) sacc[st][j] = -1e30f;
                }
            }

            // row max over lane-local 16 values + cross-lhi (lanes sharing l15)
            float rmax = sacc[0][0];
            #pragma unroll
            for (int st = 0; st < 4; st++)
            #pragma unroll
            for (int j = 0; j < 4; j++) rmax = fmaxf(rmax, sacc[st][j]);
            rmax = fmaxf(rmax, __shfl_xor(rmax, 16));
            rmax = fmaxf(rmax, __shfl_xor(rmax, 32));

            float mnew = fmaxf(m_run[qi], rmax * 0.125f);
            float rr = __expf(m_run[qi] - mnew);
            m_run[qi] = mnew;

            float psum = 0.f;
            unsigned int pk[4][2];
            #pragma unroll
            for (int st = 0; st < 4; st++) {
                float p0 = __expf(fmaf(sacc[st][0], 0.125f, -mnew));
                float p1 = __expf(fmaf(sacc[st][1], 0.125f, -mnew));
                float p2 = __expf(fmaf(sacc[st][2], 0.125f, -mnew));
                float p3 = __expf(fmaf(sacc[st][3], 0.125f, -mnew));
                psum += (p0 + p1) + (p2 + p3);
                pk[st][0] = cvt_pk_bf16(p0, p1);
                pk[st][1] = cvt_pk_bf16(p2, p3);
            }
            psum += __shfl_xor(psum, 16);
            psum += __shfl_xor(psum, 32);
            l_run[qi] = l_run[qi] * rr + psum;

            #pragma unroll
            for (int dct = 0; dct < 4; dct++)
            #pragma unroll
            for (int j = 0; j < 4; j++) oacc[qi][dct][j] *= rr;

            // P^T -> LDS: plds[qi][q_local][s_local]
            #pragma unroll
            for (int st = 0; st < 4; st++) {
                *(unsigned int*)&plds[qi][l15][st * 16 + lhi * 4 + 0] = pk[st][0];
                *(unsigned int*)&plds[qi][l15][st * 16 + lhi * 4 + 2] = pk[st][1];
            }
            // B-frag read: lane l15 = q col, k = s = ks*32 + lhi*8
            short8 pf0 = *(const short8*)&plds[qi][l15][lhi * 8];
            short8 pf1 = *(const short8*)&plds[qi][l15][32 + lhi * 8];

            #pragma unroll
            for (int dct = 0; dct < 4; dct++) {
                oacc[qi][dct] = __builtin_amdgcn_mfma_f32_16x16x32_bf16(vf[dct][0], pf0, oacc[qi][dct], 0, 0, 0);
                oacc[qi][dct] = __builtin_amdgcn_mfma_f32_16x16x32_bf16(vf[dct][1], pf1, oacc[qi][dct], 0, 0, 0);
            }
        }
    }

    // epilogue: O[d][q] -> O[(b*S+q)*HQ*HD + h*HD + d], packed pair stores
    #pragma unroll
    for (int qi = 0; qi < 2; qi++) {
        float rl = 1.0f / l_run[qi];
        const int q = qbase + qi * 16 + l15;
        unsigned short* op = O + ((size_t)(b * S_LEN + q) * HQ + h) * HD + lhi * 4;
        #pragma unroll
        for (int dct = 0; dct < 4; dct++) {
            unsigned int w0 = cvt_pk_bf16(oacc[qi][dct][0] * rl, oacc[qi][dct][1] * rl);
            unsigned int w1 = cvt_pk_bf16(oacc[qi][dct][2] * rl, oacc[qi][dct][3] * rl);
            *(unsigned int*)(op + dct * 16)     = w0;
            *(unsigned int*)(op + dct * 16 + 2) = w1;
        }
    }
}

extern "C" void kernel_launch(void* const* d_in, const int* in_sizes, int n_in,
                              void* d_out, int out_size, void* d_ws, size_t ws_size,
                              hipStream_t stream) {
    const float* x    = (const float*)d_in[0];
    const float* wq   = (const float*)d_in[1];
    const float* wk   = (const float*)d_in[2];
    const float* wv   = (const float*)d_in[3];
    const float* wo   = (const float*)d_in[4];
    const float* fcos = (const float*)d_in[5];
    const float* fsin = (const float*)d_in[6];
    float* out = (float*)d_out;

    const int M = 2 * S_LEN;              // 4096
    char* ws = (char*)d_ws;
    unsigned short* xb  = (unsigned short*)(ws);
    unsigned short* wqb = (unsigned short*)(ws + 8388608);
    unsigned short* wkb = (unsigned short*)(ws + 10485760);
    unsigned short* wvb = (unsigned short*)(ws + 11010048);
    unsigned short* wob = (unsigned short*)(ws + 11534336);
    unsigned short* Qb  = (unsigned short*)(ws + 13631488);
    unsigned short* Kb  = (unsigned short*)(ws + 22020096);
    unsigned short* Vtb = (unsigned short*)(ws + 24117248);
    unsigned short* Ab  = (unsigned short*)(ws + 26214400);

    cvt_f32_bf16<<<1024, 256, 0, stream>>>(x,  xb,  M * D_MODEL);
    cvt_f32_bf16<<<256,  256, 0, stream>>>(wq, wqb, D_MODEL * D_MODEL);
    cvt_f32_bf16<<<64,   256, 0, stream>>>(wk, wkb, HKV * HD * D_MODEL);
    cvt_f32_bf16<<<64,   256, 0, stream>>>(wv, wvb, HKV * HD * D_MODEL);
    cvt_f32_bf16<<<256,  256, 0, stream>>>(wo, wob, D_MODEL * D_MODEL);

    gemm_bt<1><<<dim3(M / 64, 16), 256, 0, stream>>>(xb, wqb, nullptr, Qb,  fcos, fsin, M, 1024, 1024);
    gemm_bt<1><<<dim3(M / 64, 4),  256, 0, stream>>>(xb, wkb, nullptr, Kb,  fcos, fsin, M, 256,  1024);
    gemm_bt<2><<<dim3(M / 64, 4),  256, 0, stream>>>(xb, wvb, nullptr, Vtb, nullptr, nullptr, M, 256, 1024);

    flash_attn<<<64 * 32, 64, 0, stream>>>(Qb, Kb, Vtb, Ab);

    gemm_bt<0><<<dim3(M / 64, 16), 256, 0, stream>>>(Ab, wob, out, nullptr, nullptr, nullptr, M, 1024, 1024);
}

// Round 3
// 150.404 us; speedup vs baseline: 2.6533x; 1.6511x over previous
//
#include <hip/hip_runtime.h>
#include <hip/hip_bf16.h>

typedef __attribute__((ext_vector_type(8))) short short8;
typedef __attribute__((ext_vector_type(4))) float floatx4;
typedef __attribute__((ext_vector_type(4))) float float4v;
typedef __attribute__((ext_vector_type(4))) unsigned short ushort4v;

#define S_LEN 2048
#define D_MODEL 1024
#define HD 64
#define HQ 16
#define HKV 4

__device__ __forceinline__ unsigned short f2bf(float f) {
    unsigned int u = __builtin_bit_cast(unsigned int, f);
    u += 0x7fffu + ((u >> 16) & 1u);   // RNE
    return (unsigned short)(u >> 16);
}

__device__ __forceinline__ unsigned int cvt_pk_bf16(float lo, float hi) {
    unsigned int r;
    asm volatile("v_cvt_pk_bf16_f32 %0, %1, %2" : "=v"(r) : "v"(lo), "v"(hi));
    return r;
}

__device__ __forceinline__ void gload16(const unsigned short* g, unsigned short* l) {
    __builtin_amdgcn_global_load_lds(
        (const __attribute__((address_space(1))) void*)g,
        (__attribute__((address_space(3))) void*)l, 16, 0, 0);
}

// ---------------- f32 -> bf16 convert ----------------
__global__ void cvt_f32_bf16(const float* __restrict__ in, unsigned short* __restrict__ out, int n) {
    int i = (blockIdx.x * blockDim.x + threadIdx.x) * 4;
    int stride = gridDim.x * blockDim.x * 4;
    for (; i < n; i += stride) {
        float4v v = *(const float4v*)(in + i);
        ushort4v o;
        o.x = f2bf(v.x); o.y = f2bf(v.y); o.z = f2bf(v.z); o.w = f2bf(v.w);
        *(ushort4v*)(out + i) = o;
    }
}

// ---------------- GEMM 128x128, BK=64, global_load_lds + XOR swizzle ----------
// C[M,N] = A[M,K] * W[N,K]^T, bf16 MFMA, f32 accum.
// EPI 0: f32 store to C [M x N]
// EPI 1: fused QKV epilogue (block-uniform by col0):
//        col0 <1024 -> Q RoPE bf16 ; <1280 -> K RoPE bf16 ; else V transposed bf16
template<int EPI>
__global__ __launch_bounds__(256) void gemm128(
    const unsigned short* __restrict__ A, const unsigned short* __restrict__ W,
    float* __restrict__ C,
    unsigned short* __restrict__ Qb, unsigned short* __restrict__ Kb, unsigned short* __restrict__ Vtb,
    const float* __restrict__ fcos, const float* __restrict__ fsin,
    int K, int N)
{
    __shared__ __align__(16) unsigned short Asm[128 * 64];
    __shared__ __align__(16) unsigned short Bsm[128 * 64];

    const int tid  = threadIdx.x;
    const int lane = tid & 63;
    const int w    = tid >> 6;
    const int wr   = w >> 1, wc = w & 1;
    const int l15  = lane & 15, lhi = lane >> 4;
    const int row0 = blockIdx.x * 128;
    const int col0 = blockIdx.y * 128;

    // staging decomposition: per issue i (0..3): phys row r = i*32 + tid/8, phys slot = tid%8
    const int r_in = tid >> 3;           // 0..31
    const int sp   = tid & 7;
    const int sl   = sp ^ (r_in & 7);    // logical slot this thread fetches (inverse swizzle)

    floatx4 acc[4][4] = {};

    for (int k0 = 0; k0 < K; k0 += 64) {
        // ---- stage A[row0..+128)[k0..+64) and W[col0..+128)[k0..+64) into LDS ----
        #pragma unroll
        for (int i = 0; i < 4; i++) {
            const int r = i * 32 + r_in;
            gload16(A + (size_t)(row0 + r) * K + k0 + sl * 8, Asm + i * 2048 + w * 512);
            gload16(W + (size_t)(col0 + r) * K + k0 + sl * 8, Bsm + i * 2048 + w * 512);
        }
        __syncthreads();   // drains vmcnt before any wave reads LDS

        short8 af[4][2], bfr[4][2];
        const int rx = l15 & 7;
        #pragma unroll
        for (int mi = 0; mi < 4; mi++) {
            const int rowa = wr * 64 + mi * 16 + l15;
            const int rowb = wc * 64 + mi * 16 + l15;
            #pragma unroll
            for (int ks = 0; ks < 2; ks++) {
                const int slot = (ks * 4 + lhi) ^ rx;
                af[mi][ks]  = *(const short8*)&Asm[rowa * 64 + slot * 8];
                bfr[mi][ks] = *(const short8*)&Bsm[rowb * 64 + slot * 8];
            }
        }

        __builtin_amdgcn_s_setprio(1);
        #pragma unroll
        for (int mi = 0; mi < 4; mi++)
        #pragma unroll
        for (int ni = 0; ni < 4; ni++) {
            acc[mi][ni] = __builtin_amdgcn_mfma_f32_16x16x32_bf16(af[mi][0], bfr[ni][0], acc[mi][ni], 0, 0, 0);
            acc[mi][ni] = __builtin_amdgcn_mfma_f32_16x16x32_bf16(af[mi][1], bfr[ni][1], acc[mi][ni], 0, 0, 0);
        }
        __builtin_amdgcn_s_setprio(0);
        __syncthreads();   // all reads done before next stage overwrites
    }

    // ---- epilogue ----
    #pragma unroll
    for (int mi = 0; mi < 4; mi++)
    #pragma unroll
    for (int ni = 0; ni < 4; ni++)
    #pragma unroll
    for (int j = 0; j < 4; j++) {
        const int row = row0 + wr * 64 + mi * 16 + lhi * 4 + j;
        const int col = col0 + wc * 64 + ni * 16 + l15;
        float v = acc[mi][ni][j];
        if (EPI == 0) {
            C[(size_t)row * D_MODEL + col] = v;
        } else {
            if (col0 < D_MODEL) {                 // ---- Q, RoPE ----
                float pv = __shfl_xor(v, 1);
                int s  = row & (S_LEN - 1);
                int fi = (col & (HD - 1)) >> 1;
                float c  = fcos[s * (HD / 2) + fi];
                float sn = fsin[s * (HD / 2) + fi];
                float o = (col & 1) ? (pv * sn + v * c) : (v * c - pv * sn);
                Qb[(size_t)row * D_MODEL + col] = f2bf(o);
            } else if (col0 < D_MODEL + 256) {    // ---- K, RoPE ----
                int ck = col - D_MODEL;
                float pv = __shfl_xor(v, 1);
                int s  = row & (S_LEN - 1);
                int fi = (ck & (HD - 1)) >> 1;
                float c  = fcos[s * (HD / 2) + fi];
                float sn = fsin[s * (HD / 2) + fi];
                float o = (ck & 1) ? (pv * sn + v * c) : (v * c - pv * sn);
                Kb[(size_t)row * 256 + ck] = f2bf(o);
            } else {                              // ---- V, transposed store ----
                int cv = col - (D_MODEL + 256);
                int b = row >> 11, s = row & (S_LEN - 1);
                int kvh = cv >> 6, d = cv & (HD - 1);
                Vtb[((size_t)(b * HKV + kvh) * HD + d) * S_LEN + s] = f2bf(v);
            }
        }
    }
}

// ---------------- Flash attention (swapped QK^T, causal, GQA) ----------------
// Q: (B,S,HQ,HD) bf16 RoPE'd, K: (B,S,HKV,HD) bf16 RoPE'd, Vt: (B,HKV,HD,S) bf16
// O: (B,S,HQ,HD) bf16.  One wave per 32 q-rows (2 q-subtiles of 16), KVBLK=64.
__global__ __launch_bounds__(64) void flash_attn(
    const unsigned short* __restrict__ Q, const unsigned short* __restrict__ Kk,
    const unsigned short* __restrict__ Vt, unsigned short* __restrict__ O)
{
    const int lane = threadIdx.x;
    const int l15 = lane & 15, lhi = lane >> 4;
    const int bid = blockIdx.x;
    const int h  = bid & 15;
    const int b  = (bid >> 4) & 1;
    const int qc = 63 - (bid >> 5);      // heavy chunks first
    const int kvh = h >> 2;
    const int qbase = qc * 32;

    __shared__ __align__(16) unsigned short plds[2][16][72];

    short8 qf[2][2];
    #pragma unroll
    for (int qi = 0; qi < 2; qi++) {
        const unsigned short* qp =
            Q + ((size_t)(b * S_LEN + qbase + qi * 16 + l15) * HQ + h) * HD + lhi * 8;
        qf[qi][0] = *(const short8*)qp;
        qf[qi][1] = *(const short8*)(qp + 32);
    }

    floatx4 oacc[2][4] = {};
    float m_run[2] = {-1e30f, -1e30f};
    float l_run[2] = {0.f, 0.f};

    const unsigned short* kbase = Kk + ((size_t)(b * S_LEN) * HKV + kvh) * HD + lhi * 8;
    const unsigned short* vbase = Vt + (size_t)((b * HKV + kvh) * HD + l15) * S_LEN + lhi * 8;

    for (int s0 = 0; s0 <= qbase + 31; s0 += 64) {
        short8 kf[4][2];
        #pragma unroll
        for (int st = 0; st < 4; st++) {
            const unsigned short* kp = kbase + (size_t)(s0 + st * 16 + l15) * (HKV * HD);
            kf[st][0] = *(const short8*)kp;
            kf[st][1] = *(const short8*)(kp + 32);
        }
        short8 vf[4][2];
        #pragma unroll
        for (int dct = 0; dct < 4; dct++) {
            const unsigned short* vp = vbase + (size_t)(dct * 16) * S_LEN + s0;
            vf[dct][0] = *(const short8*)vp;
            vf[dct][1] = *(const short8*)(vp + 32);
        }

        #pragma unroll
        for (int qi = 0; qi < 2; qi++) {
            const int qb = qbase + qi * 16;
            if (s0 > qb) continue;

            floatx4 sacc[4] = {};
            __builtin_amdgcn_s_setprio(1);
            #pragma unroll
            for (int st = 0; st < 4; st++) {
                sacc[st] = __builtin_amdgcn_mfma_f32_16x16x32_bf16(kf[st][0], qf[qi][0], sacc[st], 0, 0, 0);
                sacc[st] = __builtin_amdgcn_mfma_f32_16x16x32_bf16(kf[st][1], qf[qi][1], sacc[st], 0, 0, 0);
            }
            __builtin_amdgcn_s_setprio(0);

            const int q = qb + l15;
            if (s0 + 63 > qb) {              // diagonal tile: causal mask
                #pragma unroll
                for (int st = 0; st < 4; st++)
                #pragma unroll
                for (int j = 0; j < 4; j++) {
                    int s = s0 + st * 16 + lhi * 4 + j;
                    if (s > q) sacc[st][j] = -1e30f;
                }
            }

            float rmax = sacc[0][0];
            #pragma unroll
            for (int st = 0; st < 4; st++)
            #pragma unroll
            for (int j = 0; j < 4; j++) rmax = fmaxf(rmax, sacc[st][j]);
            rmax = fmaxf(rmax, __shfl_xor(rmax, 16));
            rmax = fmaxf(rmax, __shfl_xor(rmax, 32));
            float rscale = rmax * 0.125f;

            // T13 defer-max: skip rescale while new max within threshold
            if (!__all(rscale <= m_run[qi] + 8.0f)) {
                float mnew = fmaxf(m_run[qi], rscale);
                float rr = __expf(m_run[qi] - mnew);
                m_run[qi] = mnew;
                l_run[qi] *= rr;
                #pragma unroll
                for (int dct = 0; dct < 4; dct++)
                #pragma unroll
                for (int j = 0; j < 4; j++) oacc[qi][dct][j] *= rr;
            }
            const float mcur = m_run[qi];

            float psum = 0.f;
            unsigned int pk[4][2];
            #pragma unroll
            for (int st = 0; st < 4; st++) {
                float p0 = __expf(fmaf(sacc[st][0], 0.125f, -mcur));
                float p1 = __expf(fmaf(sacc[st][1], 0.125f, -mcur));
                float p2 = __expf(fmaf(sacc[st][2], 0.125f, -mcur));
                float p3 = __expf(fmaf(sacc[st][3], 0.125f, -mcur));
                psum += (p0 + p1) + (p2 + p3);
                pk[st][0] = cvt_pk_bf16(p0, p1);
                pk[st][1] = cvt_pk_bf16(p2, p3);
            }
            psum += __shfl_xor(psum, 16);
            psum += __shfl_xor(psum, 32);
            l_run[qi] += psum;

            #pragma unroll
            for (int st = 0; st < 4; st++) {
                *(unsigned int*)&plds[qi][l15][st * 16 + lhi * 4 + 0] = pk[st][0];
                *(unsigned int*)&plds[qi][l15][st * 16 + lhi * 4 + 2] = pk[st][1];
            }
            short8 pf0 = *(const short8*)&plds[qi][l15][lhi * 8];
            short8 pf1 = *(const short8*)&plds[qi][l15][32 + lhi * 8];

            __builtin_amdgcn_s_setprio(1);
            #pragma unroll
            for (int dct = 0; dct < 4; dct++) {
                oacc[qi][dct] = __builtin_amdgcn_mfma_f32_16x16x32_bf16(vf[dct][0], pf0, oacc[qi][dct], 0, 0, 0);
                oacc[qi][dct] = __builtin_amdgcn_mfma_f32_16x16x32_bf16(vf[dct][1], pf1, oacc[qi][dct], 0, 0, 0);
            }
            __builtin_amdgcn_s_setprio(0);
        }
    }

    #pragma unroll
    for (int qi = 0; qi < 2; qi++) {
        float rl = 1.0f / l_run[qi];
        const int q = qbase + qi * 16 + l15;
        unsigned short* op = O + ((size_t)(b * S_LEN + q) * HQ + h) * HD + lhi * 4;
        #pragma unroll
        for (int dct = 0; dct < 4; dct++) {
            unsigned int w0 = cvt_pk_bf16(oacc[qi][dct][0] * rl, oacc[qi][dct][1] * rl);
            unsigned int w1 = cvt_pk_bf16(oacc[qi][dct][2] * rl, oacc[qi][dct][3] * rl);
            *(unsigned int*)(op + dct * 16)     = w0;
            *(unsigned int*)(op + dct * 16 + 2) = w1;
        }
    }
}

extern "C" void kernel_launch(void* const* d_in, const int* in_sizes, int n_in,
                              void* d_out, int out_size, void* d_ws, size_t ws_size,
                              hipStream_t stream) {
    const float* x    = (const float*)d_in[0];
    const float* wq   = (const float*)d_in[1];
    const float* wk   = (const float*)d_in[2];
    const float* wv   = (const float*)d_in[3];
    const float* wo   = (const float*)d_in[4];
    const float* fcos = (const float*)d_in[5];
    const float* fsin = (const float*)d_in[6];
    float* out = (float*)d_out;

    char* ws = (char*)d_ws;
    unsigned short* xb    = (unsigned short*)(ws);              // 8 MB
    unsigned short* wqkvb = (unsigned short*)(ws + 8388608);    // 3 MB [1536][1024]
    unsigned short* wob   = (unsigned short*)(ws + 11534336);   // 2 MB
    unsigned short* Qb    = (unsigned short*)(ws + 13631488);   // 8 MB
    unsigned short* Kb    = (unsigned short*)(ws + 22020096);   // 2 MB
    unsigned short* Vtb   = (unsigned short*)(ws + 24117248);   // 2 MB
    unsigned short* Ab    = (unsigned short*)(ws + 26214400);   // 8 MB

    cvt_f32_bf16<<<1024, 256, 0, stream>>>(x,  xb, 4096 * 1024);
    cvt_f32_bf16<<<256,  256, 0, stream>>>(wq, wqkvb,              1024 * 1024);
    cvt_f32_bf16<<<64,   256, 0, stream>>>(wk, wqkvb + 1024 * 1024, 256 * 1024);
    cvt_f32_bf16<<<64,   256, 0, stream>>>(wv, wqkvb + 1280 * 1024, 256 * 1024);
    cvt_f32_bf16<<<256,  256, 0, stream>>>(wo, wob,                1024 * 1024);

    gemm128<1><<<dim3(32, 12), 256, 0, stream>>>(xb, wqkvb, nullptr, Qb, Kb, Vtb,
                                                 fcos, fsin, 1024, 1536);

    flash_attn<<<64 * 32, 64, 0, stream>>>(Qb, Kb, Vtb, Ab);

    gemm128<0><<<dim3(32, 8), 256, 0, stream>>>(Ab, wob, out, nullptr, nullptr, nullptr,
                                                nullptr, nullptr, 1024, 1024);
}